// Round 1
// baseline (6928.062 us; speedup 1.0000x reference)
//
#include <hip/hip_runtime.h>
#include <hip/hip_bf16.h>

#define T_TOK 1024
#define H_DIM 2048
#define E_NUM 32
#define F_DIM 1408
#define SF_DIM 5632
#define PAIRS 4096
#define PAD_PAIRS 4608
#define PAD_TILES 288

// ---------------- Router: logits, softmax, top-4, sigmoid shared gate ----------------
__global__ __launch_bounds__(256) void router_kernel(
    const float* __restrict__ x, const float* __restrict__ gw,
    const float* __restrict__ segw, float* __restrict__ logits_out,
    int* __restrict__ topk_idx, float* __restrict__ topk_w,
    float* __restrict__ seg_out, int* __restrict__ counts)
{
    __shared__ float xs[H_DIM];
    __shared__ float red[32][9];
    __shared__ float sred[256];
    __shared__ float logit[32];
    int t = blockIdx.x, tid = threadIdx.x;
    for (int i = tid; i < H_DIM; i += 256) xs[i] = x[(size_t)t * H_DIM + i];
    __syncthreads();
    // 32 expert dots: 8 threads per expert
    int e = tid >> 3, c = tid & 7;
    {
        float p = 0.f;
        const float* w = gw + (size_t)e * H_DIM + c * 256;
        const float* xv = xs + c * 256;
        for (int j = 0; j < 256; j++) p += xv[j] * w[j];
        red[e][c] = p;
    }
    // shared-expert sigmoid-gate dot
    {
        float sp = 0.f;
        for (int h = tid; h < H_DIM; h += 256) sp += xs[h] * segw[h];
        sred[tid] = sp;
    }
    __syncthreads();
    for (int s = 128; s > 0; s >>= 1) {
        if (tid < s) sred[tid] += sred[tid + s];
        __syncthreads();
    }
    if (tid < 32) {
        float s = 0.f;
        for (int j = 0; j < 8; j++) s += red[tid][j];
        logit[tid] = s;
        logits_out[(size_t)t * E_NUM + tid] = s;
    }
    __syncthreads();
    if (tid == 0) {
        seg_out[t] = 1.f / (1.f + expf(-sred[0]));
        float mx = logit[0];
        for (int j = 1; j < 32; j++) mx = fmaxf(mx, logit[j]);
        float prob[32]; float sum = 0.f;
        for (int j = 0; j < 32; j++) { prob[j] = expf(logit[j] - mx); sum += prob[j]; }
        float inv = 1.f / sum;
        unsigned used = 0u;
        for (int k = 0; k < 4; k++) {
            int bi = -1; float bv = -1.f;
            for (int j = 0; j < 32; j++)
                if (!((used >> j) & 1u) && prob[j] > bv) { bv = prob[j]; bi = j; }
            used |= (1u << bi);
            topk_idx[t * 4 + k] = bi;
            topk_w[t * 4 + k] = bv * inv;
            atomicAdd(&counts[bi], 1);
        }
    }
}

// ---------------- Prefix: padded per-expert offsets + tile map ----------------
__global__ __launch_bounds__(256) void prefix_kernel(
    const int* __restrict__ counts, int* __restrict__ poff,
    int* __restrict__ tile_expert, int* __restrict__ token_list,
    int* __restrict__ cursors)
{
    int tid = threadIdx.x;
    for (int i = tid; i < PAD_PAIRS; i += 256) token_list[i] = -1;
    for (int i = tid; i < PAD_TILES; i += 256) tile_expert[i] = -1;
    if (tid < 32) cursors[tid] = 0;
    __syncthreads();
    if (tid == 0) {
        int off = 0;
        for (int e = 0; e < E_NUM; e++) {
            poff[e] = off;
            int pc = (counts[e] + 15) & ~15;
            for (int tl = off >> 4; tl < (off + pc) >> 4; tl++) tile_expert[tl] = e;
            off += pc;
        }
        poff[E_NUM] = off;
    }
}

// ---------------- Scatter tokens into expert segments ----------------
__global__ __launch_bounds__(256) void scatter_kernel(
    const int* __restrict__ topk_idx, const float* __restrict__ topk_w,
    const int* __restrict__ poff, int* __restrict__ cursors,
    int* __restrict__ token_list, float* __restrict__ weight_list)
{
    int p = blockIdx.x * 256 + threadIdx.x; // 0..4095
    int e = topk_idx[p];
    float w = topk_w[p];
    int pos = atomicAdd(&cursors[e], 1);
    int slot = poff[e] + pos;
    token_list[slot] = p >> 2;
    weight_list[slot] = w;
}

// ---------------- MoE gate_up GEMM + SiLU*up fused ----------------
// C tile: 16 token-rows x 32 f-values (computes gate row f and up row F+f together)
__global__ __launch_bounds__(256) void moe_gup_kernel(
    const float* __restrict__ x, const float* __restrict__ gup,
    const int* __restrict__ tile_expert, const int* __restrict__ token_list,
    float* __restrict__ actbuf)
{
    int tile = blockIdx.y;
    int e = tile_expert[tile];
    if (e < 0) return;
    int f0 = blockIdx.x * 32;
    __shared__ float As[16][33];
    __shared__ float Bs[64][33];
    __shared__ int ts[16];
    int tid = threadIdx.x;
    if (tid < 16) ts[tid] = token_list[tile * 16 + tid];
    __syncthreads();
    int m = tid & 15, fi = tid >> 4;
    int fl = fi * 2;
    float g0 = 0, g1 = 0, u0 = 0, u1 = 0;
    const float* wbase = gup + (size_t)e * (2 * F_DIM) * H_DIM;
    for (int k0 = 0; k0 < H_DIM; k0 += 32) {
        {
            int r = tid >> 4, c = (tid & 15) * 2;
            int tok = ts[r];
            float vx = 0.f, vy = 0.f;
            if (tok >= 0) {
                const float2 v = *(const float2*)&x[(size_t)tok * H_DIM + k0 + c];
                vx = v.x; vy = v.y;
            }
            As[r][c] = vx; As[r][c + 1] = vy;
        }
#pragma unroll
        for (int i = 0; i < 4; i++) {
            int e2 = tid + i * 256;
            int r = e2 >> 4, c = (e2 & 15) * 2;
            int grow = (r < 32) ? (f0 + r) : (F_DIM + f0 + (r - 32));
            const float2 v = *(const float2*)&wbase[(size_t)grow * H_DIM + k0 + c];
            Bs[r][c] = v.x; Bs[r][c + 1] = v.y;
        }
        __syncthreads();
#pragma unroll
        for (int kk = 0; kk < 32; kk++) {
            float a = As[m][kk];
            g0 += a * Bs[fl][kk];
            g1 += a * Bs[fl + 1][kk];
            u0 += a * Bs[32 + fl][kk];
            u1 += a * Bs[32 + fl + 1][kk];
        }
        __syncthreads();
    }
    size_t row = (size_t)(tile * 16 + m);
    float a0 = g0 / (1.f + __expf(-g0)) * u0;
    float a1 = g1 / (1.f + __expf(-g1)) * u1;
    actbuf[row * F_DIM + f0 + fl] = a0;
    actbuf[row * F_DIM + f0 + fl + 1] = a1;
}

// ---------------- MoE down GEMM, weighted atomicAdd into out ----------------
__global__ __launch_bounds__(256) void moe_down_kernel(
    const float* __restrict__ actbuf, const float* __restrict__ dw,
    const int* __restrict__ tile_expert, const int* __restrict__ token_list,
    const float* __restrict__ weight_list, float* __restrict__ out)
{
    int tile = blockIdx.y;
    int e = tile_expert[tile];
    if (e < 0) return;
    int h0 = blockIdx.x * 64;
    __shared__ float As[16][33];
    __shared__ float Bs[64][33];
    __shared__ int ts[16];
    __shared__ float wl[16];
    int tid = threadIdx.x;
    if (tid < 16) {
        ts[tid] = token_list[tile * 16 + tid];
        wl[tid] = weight_list[tile * 16 + tid];
    }
    __syncthreads();
    int m = tid & 15, hi = tid >> 4;
    float acc[4] = {0, 0, 0, 0};
    const float* wbase = dw + (size_t)e * H_DIM * F_DIM;
    for (int k0 = 0; k0 < F_DIM; k0 += 32) {
        {
            int r = tid >> 4, c = (tid & 15) * 2;
            const float2 v = *(const float2*)&actbuf[(size_t)(tile * 16 + r) * F_DIM + k0 + c];
            As[r][c] = v.x; As[r][c + 1] = v.y;
        }
#pragma unroll
        for (int i = 0; i < 4; i++) {
            int e2 = tid + i * 256;
            int r = e2 >> 4, c = (e2 & 15) * 2;
            const float2 v = *(const float2*)&wbase[(size_t)(h0 + r) * F_DIM + k0 + c];
            Bs[r][c] = v.x; Bs[r][c + 1] = v.y;
        }
        __syncthreads();
#pragma unroll
        for (int kk = 0; kk < 32; kk++) {
            float a = As[m][kk];
#pragma unroll
            for (int j = 0; j < 4; j++) acc[j] += a * Bs[hi * 4 + j][kk];
        }
        __syncthreads();
    }
    int tok = ts[m];
    if (tok >= 0) {
        float w = wl[m];
#pragma unroll
        for (int j = 0; j < 4; j++)
            atomicAdd(&out[(size_t)tok * H_DIM + h0 + hi * 4 + j], w * acc[j]);
    }
}

// ---------------- Shared expert gate/up + SiLU*up ----------------
__global__ __launch_bounds__(256) void shared_gup_kernel(
    const float* __restrict__ x, const float* __restrict__ wg,
    const float* __restrict__ wu, float* __restrict__ sact)
{
    int tile = blockIdx.y;          // 0..63 token tiles
    int f0 = blockIdx.x * 32;       // 0..5631
    __shared__ float As[16][33];
    __shared__ float Bs[64][33];
    int tid = threadIdx.x;
    int m = tid & 15, fi = tid >> 4;
    int fl = fi * 2;
    float g0 = 0, g1 = 0, u0 = 0, u1 = 0;
    for (int k0 = 0; k0 < H_DIM; k0 += 32) {
        {
            int r = tid >> 4, c = (tid & 15) * 2;
            int tok = tile * 16 + r;
            const float2 v = *(const float2*)&x[(size_t)tok * H_DIM + k0 + c];
            As[r][c] = v.x; As[r][c + 1] = v.y;
        }
#pragma unroll
        for (int i = 0; i < 4; i++) {
            int e2 = tid + i * 256;
            int r = e2 >> 4, c = (e2 & 15) * 2;
            const float* wrow = (r < 32) ? &wg[(size_t)(f0 + r) * H_DIM]
                                         : &wu[(size_t)(f0 + r - 32) * H_DIM];
            const float2 v = *(const float2*)&wrow[k0 + c];
            Bs[r][c] = v.x; Bs[r][c + 1] = v.y;
        }
        __syncthreads();
#pragma unroll
        for (int kk = 0; kk < 32; kk++) {
            float a = As[m][kk];
            g0 += a * Bs[fl][kk];
            g1 += a * Bs[fl + 1][kk];
            u0 += a * Bs[32 + fl][kk];
            u1 += a * Bs[32 + fl + 1][kk];
        }
        __syncthreads();
    }
    size_t row = (size_t)(tile * 16 + m);
    float a0 = g0 / (1.f + __expf(-g0)) * u0;
    float a1 = g1 / (1.f + __expf(-g1)) * u1;
    sact[row * SF_DIM + f0 + fl] = a0;
    sact[row * SF_DIM + f0 + fl + 1] = a1;
}

// ---------------- Shared expert down, sigmoid-gated atomicAdd into out ----------------
__global__ __launch_bounds__(256) void shared_down_kernel(
    const float* __restrict__ sact, const float* __restrict__ sdw,
    const float* __restrict__ seg, float* __restrict__ out)
{
    int tile = blockIdx.y;      // token tile
    int h0 = blockIdx.x * 64;
    __shared__ float As[16][33];
    __shared__ float Bs[64][33];
    int tid = threadIdx.x;
    int m = tid & 15, hi = tid >> 4;
    float acc[4] = {0, 0, 0, 0};
    for (int k0 = 0; k0 < SF_DIM; k0 += 32) {
        {
            int r = tid >> 4, c = (tid & 15) * 2;
            const float2 v = *(const float2*)&sact[(size_t)(tile * 16 + r) * SF_DIM + k0 + c];
            As[r][c] = v.x; As[r][c + 1] = v.y;
        }
#pragma unroll
        for (int i = 0; i < 4; i++) {
            int e2 = tid + i * 256;
            int r = e2 >> 4, c = (e2 & 15) * 2;
            const float2 v = *(const float2*)&sdw[(size_t)(h0 + r) * SF_DIM + k0 + c];
            Bs[r][c] = v.x; Bs[r][c + 1] = v.y;
        }
        __syncthreads();
#pragma unroll
        for (int kk = 0; kk < 32; kk++) {
            float a = As[m][kk];
#pragma unroll
            for (int j = 0; j < 4; j++) acc[j] += a * Bs[hi * 4 + j][kk];
        }
        __syncthreads();
    }
    int tok = tile * 16 + m;
    float scale = seg[tok];
#pragma unroll
    for (int j = 0; j < 4; j++)
        atomicAdd(&out[(size_t)tok * H_DIM + h0 + hi * 4 + j], scale * acc[j]);
}

extern "C" void kernel_launch(void* const* d_in, const int* in_sizes, int n_in,
                              void* d_out, int out_size, void* d_ws, size_t ws_size,
                              hipStream_t stream) {
    const float* x    = (const float*)d_in[0];
    const float* gw   = (const float*)d_in[1];
    const float* gup  = (const float*)d_in[2];
    const float* dw   = (const float*)d_in[3];
    const float* sgw  = (const float*)d_in[4];
    const float* suw  = (const float*)d_in[5];
    const float* sdw  = (const float*)d_in[6];
    const float* segw = (const float*)d_in[7];
    float* out        = (float*)d_out;              // 1024*2048
    float* logits_out = out + (size_t)T_TOK * H_DIM; // 1024*32

    // workspace layout (floats)
    float* wsf = (float*)d_ws;
    int*   topk_idx    = (int*)wsf;                       // 4096
    float* topk_w      = wsf + 4096;                      // 4096
    int*   counts      = (int*)(wsf + 8192);              // 32
    int*   poff        = counts + 32;                     // 33
    int*   cursors     = poff + 33;                       // 32
    int*   tile_expert = cursors + 32;                    // 288
    int*   token_list  = tile_expert + 288;               // 4608
    float* weight_list = (float*)(token_list + 4608);     // 4608
    float* seg         = weight_list + 4608;              // 1024
    float* actbuf      = wsf + 18944;                     // 4608*1408 floats (reused: 1024*5632)

    hipMemsetAsync(d_out, 0, (size_t)out_size * sizeof(float), stream);
    hipMemsetAsync(counts, 0, 32 * sizeof(int), stream);

    router_kernel<<<T_TOK, 256, 0, stream>>>(x, gw, segw, logits_out, topk_idx, topk_w, seg, counts);
    prefix_kernel<<<1, 256, 0, stream>>>(counts, poff, tile_expert, token_list, cursors);
    scatter_kernel<<<PAIRS / 256, 256, 0, stream>>>(topk_idx, topk_w, poff, cursors, token_list, weight_list);

    moe_gup_kernel<<<dim3(F_DIM / 32, PAD_TILES), 256, 0, stream>>>(x, gup, tile_expert, token_list, actbuf);
    moe_down_kernel<<<dim3(H_DIM / 64, PAD_TILES), 256, 0, stream>>>(actbuf, dw, tile_expert, token_list, weight_list, out);

    shared_gup_kernel<<<dim3(SF_DIM / 32, T_TOK / 16), 256, 0, stream>>>(x, sgw, suw, actbuf);
    shared_down_kernel<<<dim3(H_DIM / 64, T_TOK / 16), 256, 0, stream>>>(actbuf, sdw, seg, out);
}